// Round 4
// baseline (185.725 us; speedup 1.0000x reference)
//
#include <hip/hip_runtime.h>

#define HW 96
#define NPIX 9216
#define QN 192
#define SCALE 0.17677669529663687f
#define NT 576

// XOR-swizzled LDS word addresses (linear rows of 64 words).
__device__ __forceinline__ int xswz(int row, int col) {
    return row * 64 + (((col & 60) ^ (((row >> 2) & 7) << 2)) | (col & 3));
}
__device__ __forceinline__ int wswz(int row, int col) {
    return row * 64 + (((col & 60) ^ ((row & 7) << 2)) | (col & 3));
}

template <int PAT>
__device__ __forceinline__ float swzf(float v) {
    return __int_as_float(__builtin_amdgcn_ds_swizzle(__float_as_int(v), PAT));
}

// PV chain: neighbor n owned by lane ln=n&15 slot kn=n>>4; broadcast w via
// ds_swizzle (and=0x10 keeps 16-group, or=ln). a=n/7, b=n%7 compile-time.
template <int N>
struct PVChain {
    static __device__ __forceinline__ void run(const float* __restrict__ vbase,
                                               const float* __restrict__ wk,
                                               float& a0, float& a1, float& c0, float& c1) {
        PVChain<N - 1>::run(vbase, wk, a0, a1, c0, c1);
        constexpr int kn = N >> 4, ln = N & 15;
        constexpr int av = N / 7, bv = N % 7;
        float w = __int_as_float(__builtin_amdgcn_ds_swizzle(
                      __float_as_int(wk[kn]), (ln << 5) | 0x10));
        const float2 v = *(const float2*)(vbase + (av * HW + bv) * QN);
        if (N & 1) { c0 = fmaf(w, v.x, c0); c1 = fmaf(w, v.y, c1); }
        else       { a0 = fmaf(w, v.x, a0); a1 = fmaf(w, v.y, a1); }
    }
};
template <>
struct PVChain<-1> {
    static __device__ __forceinline__ void run(const float*, const float*,
                                               float&, float&, float&, float&) {}
};

// 18px x 192j x 64c GEMM from LDS. 576 threads: pxg=t%9 (2 px), jo=t/9 (3 j).
__device__ __forceinline__ void qkv_gemm(const float* __restrict__ xs,
                                         const float* __restrict__ ws,
                                         const float* __restrict__ qb,
                                         float* __restrict__ qkv,
                                         int i0, int j0c, int t)
{
    const int pxg = t % 9, jo = t / 9;
    const int jb = jo * 3;
    float acc[2][3];
    #pragma unroll
    for (int jj = 0; jj < 3; ++jj) {
        float bv = qb[jb + jj];
        acc[0][jj] = bv; acc[1][jj] = bv;
    }
    #pragma unroll
    for (int cc = 0; cc < 16; ++cc) {
        float4 xv[2], wv[3];
        #pragma unroll
        for (int ii = 0; ii < 2; ++ii)
            xv[ii] = *(const float4*)&xs[xswz(pxg * 2 + ii, cc * 4)];
        #pragma unroll
        for (int jj = 0; jj < 3; ++jj)
            wv[jj] = *(const float4*)&ws[wswz(jb + jj, cc * 4)];
        #pragma unroll
        for (int ii = 0; ii < 2; ++ii)
            #pragma unroll
            for (int jj = 0; jj < 3; ++jj) {
                acc[ii][jj] = fmaf(xv[ii].x, wv[jj].x, acc[ii][jj]);
                acc[ii][jj] = fmaf(xv[ii].y, wv[jj].y, acc[ii][jj]);
                acc[ii][jj] = fmaf(xv[ii].z, wv[jj].z, acc[ii][jj]);
                acc[ii][jj] = fmaf(xv[ii].w, wv[jj].w, acc[ii][jj]);
            }
    }
    #pragma unroll
    for (int ii = 0; ii < 2; ++ii) {
        int px = pxg * 2 + ii;
        float* o = qkv + ((i0 + px / 3) * HW + j0c + px % 3) * QN + jb;
        o[0] = acc[ii][0]; o[1] = acc[ii][1]; o[2] = acc[ii][2];
    }
}

__global__ __launch_bounds__(NT) void k_qkv0(const float* __restrict__ x,
                                             const float* __restrict__ qw,
                                             const float* __restrict__ qb,
                                             float* __restrict__ qkv)
{
    __shared__ float xs[18 * 64];
    __shared__ float ws[QN * 64];
    const int t = threadIdx.x;
    const int i0 = (blockIdx.x >> 5) * 6, j0c = (blockIdx.x & 31) * 3;
    #pragma unroll
    for (int it = 0; it < 2; ++it) {
        int l = it * NT + t;
        int px = l % 18, c = l / 18;
        xs[xswz(px, c)] = x[c * NPIX + (i0 + px / 3) * HW + j0c + px % 3];
    }
    #pragma unroll
    for (int it = 0; it < 6; ++it) {
        int l = it * NT + t;
        if (l < 3072) {
            int j = l >> 4, cs = (l & 15) << 2;
            *(float4*)&ws[wswz(j, cs)] = *(const float4*)&qw[j * 64 + cs];
        }
    }
    __syncthreads();
    qkv_gemm(xs, ws, qb, qkv, i0, j0c, t);
}

// Fused stage: hybrid attention (neighbor-split QK, cross-lane softmax,
// dim-split PV w/ swizzle broadcast) + proj + (next qkv | final output).
// 576 threads = 36 groups (18 px x 2 heads) x 16 lanes.
template <int HASPREV, int LAST>
__global__ __launch_bounds__(NT) void k_stage(const float* __restrict__ qkv,
                                              const float* __restrict__ rpb,
                                              const float* __restrict__ prev,
                                              float* __restrict__ cur,
                                              const float* __restrict__ pw,
                                              const float* __restrict__ pb,
                                              const float* __restrict__ qw,
                                              const float* __restrict__ qb,
                                              float* __restrict__ qkvn,
                                              float* __restrict__ outp)
{
    __shared__ float xs[18 * 64];
    __shared__ float ws[QN * 64];
    const int t = threadIdx.x;
    const int i0 = (blockIdx.x >> 5) * 6, j0c = (blockIdx.x & 31) * 3;
    // stage proj weights (consumed after barrier 1)
    #pragma unroll
    for (int it = 0; it < 2; ++it) {
        int l = it * NT + t;
        if (l < 1024) {
            int j = l >> 4, cs = (l & 15) << 2;
            *(float4*)&ws[wswz(j, cs)] = *(const float4*)&pw[j * 64 + cs];
        }
    }
    // ---------------- attention ----------------
    const int r = t & 15, g = t >> 4;
    const int h = g & 1, pl = g >> 1;
    const int i = i0 + pl / 3, jx = j0c + pl % 3;
    const int p = i * HW + jx;
    int si = i - 3;  si = si < 0 ? 0 : (si > 89 ? 89 : si);
    int sj = jx - 3; sj = sj < 0 ? 0 : (sj > 89 ? 89 : sj);
    float4 q[8];
    {
        const float4* qp = (const float4*)(qkv + p * QN + h * 32);
        #pragma unroll
        for (int d = 0; d < 8; ++d) q[d] = qp[d];
    }
    float pr[4] = {0.f, 0.f, 0.f, 0.f};
    if (HASPREV) {
        float4 z = *(const float4*)(prev + (p * 2 + h) * 64 + r * 4);
        pr[0] = z.x; pr[1] = z.y; pr[2] = z.z; pr[3] = z.w;
    }
    const float* kbase = qkv + (si * HW + sj) * QN + 64 + h * 32;
    float lg[4];
    int aa[4], bb[4];
    #pragma unroll
    for (int k = 0; k < 4; ++k) {
        int n = (k << 4) | r;
        int a = (n * 147) >> 10;           // n/7 for n<=62
        int b = n - a * 7;
        aa[k] = a; bb[k] = b;
        const float4* kp = (const float4*)(kbase + (a * HW + b) * QN);
        float s0 = 0.f, s1 = 0.f, s2 = 0.f, s3 = 0.f;
        #pragma unroll
        for (int d = 0; d < 8; ++d) {
            float4 kv = kp[d];
            s0 = fmaf(q[d].x, kv.x, s0);
            s1 = fmaf(q[d].y, kv.y, s1);
            s2 = fmaf(q[d].z, kv.z, s2);
            s3 = fmaf(q[d].w, kv.w, s3);
        }
        lg[k] = (s0 + s1) + (s2 + s3);
    }
    {
        const float* rp = rpb + h * 169;
        const int rh0 = si - i + 6, rw0 = sj - jx + 6;
        #pragma unroll
        for (int k = 0; k < 4; ++k) {
            int n = (k << 4) | r;
            float v = fmaf(lg[k], SCALE, rp[(rh0 + aa[k]) * 13 + rw0 + bb[k]] + pr[k]);
            lg[k] = (n <= 48) ? v : -1e30f;
        }
    }
    // softmax across the 16-lane group
    float mx = fmaxf(fmaxf(lg[0], lg[1]), fmaxf(lg[2], lg[3]));
    mx = fmaxf(mx, swzf<0x041F>(mx));
    mx = fmaxf(mx, swzf<0x081F>(mx));
    mx = fmaxf(mx, swzf<0x101F>(mx));
    mx = fmaxf(mx, swzf<0x201F>(mx));
    float wk[4];
    float sum = 0.f;
    #pragma unroll
    for (int k = 0; k < 4; ++k) { wk[k] = expf(lg[k] - mx); sum += wk[k]; }
    sum += swzf<0x041F>(sum);
    sum += swzf<0x081F>(sum);
    sum += swzf<0x101F>(sum);
    sum += swzf<0x201F>(sum);
    const float inv = 1.f / sum;
    wk[0] *= inv; wk[1] *= inv; wk[2] *= inv; wk[3] *= inv;
    if (!LAST)
        *(float4*)(cur + (p * 2 + h) * 64 + r * 4) = make_float4(wk[0], wk[1], wk[2], wk[3]);
    // PV: dim-split (2 dims/lane), weights broadcast in-wave
    {
        const float* vbase = qkv + (si * HW + sj) * QN + 128 + h * 32 + r * 2;
        float a0 = 0.f, a1 = 0.f, c0 = 0.f, c1 = 0.f;
        PVChain<48>::run(vbase, wk, a0, a1, c0, c1);
        *(float2*)&xs[xswz(pl, h * 32 + r * 2)] = make_float2(a0 + c0, a1 + c1);
    }
    __syncthreads();                      // attn tile in xs, ws staged
    // ---------------- proj: pxg=t%9 (2 px), jo=t/9 (1 j) ----------------
    const int pxg = t % 9, jo = t / 9;
    float pa0 = pb[jo], pa1 = pa0;
    #pragma unroll
    for (int cc = 0; cc < 16; ++cc) {
        float4 xv0 = *(const float4*)&xs[xswz(pxg * 2, cc * 4)];
        float4 xv1 = *(const float4*)&xs[xswz(pxg * 2 + 1, cc * 4)];
        float4 wv  = *(const float4*)&ws[wswz(jo, cc * 4)];
        pa0 = fmaf(xv0.x, wv.x, pa0); pa0 = fmaf(xv0.y, wv.y, pa0);
        pa0 = fmaf(xv0.z, wv.z, pa0); pa0 = fmaf(xv0.w, wv.w, pa0);
        pa1 = fmaf(xv1.x, wv.x, pa1); pa1 = fmaf(xv1.y, wv.y, pa1);
        pa1 = fmaf(xv1.z, wv.z, pa1); pa1 = fmaf(xv1.w, wv.w, pa1);
    }
    __syncthreads();                      // all proj reads done
    xs[xswz(pxg * 2, jo)]     = pa0;
    xs[xswz(pxg * 2 + 1, jo)] = pa1;
    if (!LAST) {
        #pragma unroll
        for (int it = 0; it < 6; ++it) {
            int l = it * NT + t;
            if (l < 3072) {
                int j = l >> 4, cs = (l & 15) << 2;
                *(float4*)&ws[wswz(j, cs)] = *(const float4*)&qw[j * 64 + cs];
            }
        }
    }
    __syncthreads();                      // xh in xs, next weights in ws
    if (LAST) {
        #pragma unroll
        for (int it = 0; it < 2; ++it) {
            int l = it * NT + t;
            int px = l % 18, c = l / 18;
            outp[c * NPIX + (i0 + px / 3) * HW + j0c + px % 3] = xs[xswz(px, c)];
        }
        return;
    }
    qkv_gemm(xs, ws, qb, qkvn, i0, j0c, t);
}

extern "C" void kernel_launch(void* const* d_in, const int* in_sizes, int n_in,
                              void* d_out, int out_size, void* d_ws, size_t ws_size,
                              hipStream_t stream)
{
    const float* x   = (const float*)d_in[0];
    const float* qw  = (const float*)d_in[1];   // (3,192,64)
    const float* qb  = (const float*)d_in[2];   // (3,192)
    const float* pw  = (const float*)d_in[3];   // (3,64,64)
    const float* pb  = (const float*)d_in[4];   // (3,64)
    const float* rpb = (const float*)d_in[5];   // (3,2,13,13)
    float* out = (float*)d_out;
    float* ws  = (float*)d_ws;

    float* qkvA = ws;                    // 1,769,472 floats
    float* qkvB = qkvA + 1769472;        // 1,769,472
    float* attA = qkvB + 1769472;        // 1,179,648 (18432 * 64)
    float* attB = attA + 1179648;        // 1,179,648  (~23.6 MB total)

    k_qkv0<<<512, NT, 0, stream>>>(x, qw, qb, qkvA);
    k_stage<0, 0><<<512, NT, 0, stream>>>(qkvA, rpb,       nullptr, attA,
                                          pw,        pb,       qw + 12288, qb + 192, qkvB, nullptr);
    k_stage<1, 0><<<512, NT, 0, stream>>>(qkvB, rpb + 338, attA,    attB,
                                          pw + 4096, pb + 64,  qw + 24576, qb + 384, qkvA, nullptr);
    k_stage<1, 1><<<512, NT, 0, stream>>>(qkvA, rpb + 676, attB,    nullptr,
                                          pw + 8192, pb + 128, nullptr,    nullptr,  nullptr, out);
}